// Round 4
// baseline (599.442 us; speedup 1.0000x reference)
//
#include <hip/hip_runtime.h>
#include <hip/hip_bf16.h>

#define NODELEN 17949
#define NN 512
#define NE 4096
#define H2 768
#define EMB 128
#define IN_DIM (2 * NODELEN)      // 35898
#define KP1 35904                 // IN_DIM padded to 64 (561 * 64)
#define KITERS1 561
#define SPLITS 24
#define KCHUNK1 24                // ceil(561/24)
#define FPAD 18048                // NODELEN padded to 128 (141 * 128)
#define RPAD4 35968               // IN_DIM padded to 128 (281 * 128)

#define BM 128
#define BN 128
#define BK 64

typedef __bf16 bf16x8 __attribute__((ext_vector_type(8)));
typedef float f32x4 __attribute__((ext_vector_type(4)));

#define GPTR(p) ((const __attribute__((address_space(1))) void*)(p))
#define LPTR(p) ((__attribute__((address_space(3))) void*)(p))

// ---------------- graph prep (dense adjacency) ----------------

__global__ void k_zero_int(int* p, int n) {
    int i = blockIdx.x * 256 + threadIdx.x;
    if (i < n) p[i] = 0;
}

__global__ void k_zero_f4(float4* p, int n4) {
    int i = blockIdx.x * 256 + threadIdx.x;
    if (i < n4) p[i] = make_float4(0.f, 0.f, 0.f, 0.f);
}

__global__ void k_deg(const int* __restrict__ dst, int* __restrict__ cnt) {
    int e = blockIdx.x * 256 + threadIdx.x;
    if (e < NE) atomicAdd(&cnt[dst[e]], 1);
}

__global__ void k_invdeg(const int* __restrict__ cnt, float* __restrict__ invdeg) {
    int i = blockIdx.x * 256 + threadIdx.x;
    if (i < NN) {
        int c = cnt[i];
        invdeg[i] = 1.0f / (float)(c > 1 ? c : 1);
    }
}

// A[dst][src] += 1/deg[dst]  (duplicates accumulate identical values -> order-safe)
__global__ void k_scatter(const int* __restrict__ src, const int* __restrict__ dst,
                          const float* __restrict__ invdeg, float* __restrict__ A) {
    int e = blockIdx.x * 256 + threadIdx.x;
    if (e < NE) {
        int d = dst[e];
        atomicAdd(&A[(size_t)d * NN + src[e]], invdeg[d]);
    }
}

// A2b = bf16(A @ A), exploiting row sparsity (uniform branch on broadcast value)
__global__ void k_a2(const float* __restrict__ A, __bf16* __restrict__ A2b) {
    int i = blockIdx.x;
    int t = threadIdx.x;   // 256
    __shared__ float row[NN];
    row[t] = A[(size_t)i * NN + t];
    row[t + 256] = A[(size_t)i * NN + 256 + t];
    __syncthreads();
    float a0 = 0.f, a1 = 0.f;
    for (int s = 0; s < NN; ++s) {
        float a = row[s];
        if (a != 0.f) {
            a0 += a * A[(size_t)s * NN + t];
            a1 += a * A[(size_t)s * NN + 256 + t];
        }
    }
    A2b[(size_t)i * NN + t] = (__bf16)a0;
    A2b[(size_t)i * NN + 256 + t] = (__bf16)a1;
}

// Fused: xT[f][s] = bf16(x[s][f]) for f < FPAD (zero rows beyond NODELEN)
// AND embb x-half (col0 zero). Reads x exactly once.
__global__ void k_xt_emb(const float* __restrict__ x, __bf16* __restrict__ xT,
                         __bf16* __restrict__ embb) {
    __shared__ float t[64][65];
    int f0 = blockIdx.x * 64, s0 = blockIdx.y * 64;
    int tx = threadIdx.x & 63, ty = threadIdx.x >> 6;   // ty 0..3
#pragma unroll
    for (int r = 0; r < 16; ++r) {
        int f = f0 + tx;
        int s = s0 + ty * 16 + r;
        float v = (f < NODELEN) ? x[(size_t)s * NODELEN + f] : 0.f;
        t[ty * 16 + r][tx] = v;
        if (f < NODELEN)
            embb[(size_t)s * KP1 + f] = (__bf16)((f == 0) ? 0.f : v);
    }
    __syncthreads();
#pragma unroll
    for (int r = 0; r < 16; ++r) {
        int f = f0 + ty * 16 + r;
        if (f < FPAD) xT[(size_t)f * NN + s0 + tx] = (__bf16)t[tx][ty * 16 + r];
    }
}

// zero pad cols [IN_DIM, KP1) of embb
__global__ void k_pad(__bf16* __restrict__ embb) {
    int i = blockIdx.x * 256 + threadIdx.x;
    const int PAD = KP1 - IN_DIM;   // 6
    if (i < NN * PAD) {
        int n = i / PAD, c = i % PAD;
        embb[(size_t)n * KP1 + IN_DIM + c] = (__bf16)0.f;
    }
}

// ---------------- MFMA GEMM: C[m][n] = sum_k A[m][k] * B[n][k] ----------------
// m97-proven structure: single-buffer LINEAR LDS (32 KB), 2 barriers/K-step,
// TLP from 4 blocks/CU hides latency, XCD-swizzled block mapping.
// A: bf16, staged via global_load_lds dwordx4 (wave-uniform base + lane*16).
// B: BF32 ? f32 reg-staged with on-the-fly bf16 convert (saves the k_cvt
//    round-trip: 110 MB read vs 220 MB cvt+reread)  : bf16 via global_load_lds.
// Staging geometry (both sides): round rr 0..3, thread t -> row rr*32 + t/8,
// cols (t&7)*8; LDS byte addr = rr*4096 + t*16 (conflict-free writes).
// EPI: 0 = split-K partials, 1 = f32 out + bias, 2 = bf16 out into embb h2-half.

template <int EPI, bool BF32>
__device__ __forceinline__ void gemm_body(
        const __bf16* __restrict__ A, int lda,
        const void* __restrict__ Bv, int ldb,
        int Nvalid, int Brows, int Kvalid, int kIters, int kChunk,
        float* __restrict__ Cf, int ldc, const float* __restrict__ bias,
        __bf16* __restrict__ Cb) {
    __shared__ __align__(16) __bf16 As[BM * BK];   // linear [row][64], 16 KB
    __shared__ __align__(16) __bf16 Bs[BN * BK];   // linear [row][64], 16 KB

    const int tid = threadIdx.x;

    // ---- XCD-aware bijective swizzle (dispatch fid -> XCD = fid % 8) ----
    const int gx = gridDim.x, gy = gridDim.y;
    const int nwg = gx * gy * (int)gridDim.z;
    const int fid = blockIdx.x + gx * (blockIdx.y + gy * blockIdx.z);
    const int q = nwg >> 3, r = nwg & 7;
    const int xcd = fid & 7, idx = fid >> 3;
    const int lid = (xcd < r) ? xcd * (q + 1) + idx
                              : r * (q + 1) + (xcd - r) * q + idx;
    const int m0 = (lid % gx) * BM;
    const int rem = lid / gx;
    const int n0 = (rem % gy) * BN;
    const int z = rem / gy;

    int it0 = z * kChunk;
    int it1 = it0 + kChunk;
    if (it1 > kIters) it1 = kIters;

    const int wave = tid >> 6;
    const int lane = tid & 63;
    const int wm = (wave & 1) * 64;
    const int wn = (wave >> 1) * 64;
    const int fl = lane & 15;
    const int fq = lane >> 4;

    const __bf16* Abase = A + (size_t)(m0 + (tid >> 3)) * lda + (tid & 7) * 8;
    char* AsW = (char*)As + wave * 1024;
    const __bf16* Bbase_h = (const __bf16*)Bv + (size_t)(n0 + (tid >> 3)) * ldb + (tid & 7) * 8;
    char* BsW = (char*)Bs + wave * 1024;
    const float* Bf = (const float*)Bv;
    const int btrow = n0 + (tid >> 3);          // base B row for rr=0
    const int bkoff = (tid & 7) * 8;            // col offset within K-tile

    f32x4 acc[4][4] = {};

    for (int it = it0; it < it1; ++it) {
        const int k0 = it * BK;
        // A: async global->LDS
        const __bf16* Ag = Abase + k0;
#pragma unroll
        for (int rr = 0; rr < 4; ++rr)
            __builtin_amdgcn_global_load_lds(
                GPTR(Ag + (size_t)rr * 32 * lda), LPTR(AsW + rr * 4096), 16, 0, 0);
        // B
        if (BF32) {
            // f32 reg-stage + convert; regs die inside this block
#pragma unroll
            for (int rr = 0; rr < 4; ++rr) {
                const int brow = btrow + rr * 32;
                const int kc = k0 + bkoff;
                const float* Bg = Bf + (size_t)brow * ldb + kc;
                float4 f0, f1;
                if (brow < Brows && kc + 8 <= Kvalid) {
                    f0 = ((const float4*)Bg)[0];
                    f1 = ((const float4*)Bg)[1];
                } else {
                    float tv[8];
#pragma unroll
                    for (int j = 0; j < 8; ++j)
                        tv[j] = (brow < Brows && kc + j < Kvalid) ? Bg[j] : 0.f;
                    f0 = make_float4(tv[0], tv[1], tv[2], tv[3]);
                    f1 = make_float4(tv[4], tv[5], tv[6], tv[7]);
                }
                __align__(16) __bf16 o[8];
                o[0] = (__bf16)f0.x; o[1] = (__bf16)f0.y;
                o[2] = (__bf16)f0.z; o[3] = (__bf16)f0.w;
                o[4] = (__bf16)f1.x; o[5] = (__bf16)f1.y;
                o[6] = (__bf16)f1.z; o[7] = (__bf16)f1.w;
                *(uint4*)((char*)Bs + rr * 4096 + tid * 16) = *(uint4*)o;
            }
        } else {
            const __bf16* Bg = Bbase_h + k0;
#pragma unroll
            for (int rr = 0; rr < 4; ++rr)
                __builtin_amdgcn_global_load_lds(
                    GPTR(Bg + (size_t)rr * 32 * ldb), LPTR(BsW + rr * 4096), 16, 0, 0);
        }
        __syncthreads();   // drains vmcnt (GLL) + lgkmcnt (ds_write) before s_barrier

#pragma unroll
        for (int ks = 0; ks < 2; ++ks) {
            const int kk = ks * 32 + fq * 8;
            bf16x8 af[4], bfr[4];
#pragma unroll
            for (int i = 0; i < 4; ++i)
                af[i] = *(const bf16x8*)&As[(wm + i * 16 + fl) * BK + kk];
#pragma unroll
            for (int j = 0; j < 4; ++j)
                bfr[j] = *(const bf16x8*)&Bs[(wn + j * 16 + fl) * BK + kk];
#pragma unroll
            for (int i = 0; i < 4; ++i)
#pragma unroll
                for (int j = 0; j < 4; ++j)
                    acc[i][j] = __builtin_amdgcn_mfma_f32_16x16x32_bf16(
                        af[i], bfr[j], acc[i][j], 0, 0, 0);
        }
        __syncthreads();
    }

    // epilogue
#pragma unroll
    for (int i = 0; i < 4; ++i) {
#pragma unroll
        for (int j = 0; j < 4; ++j) {
#pragma unroll
            for (int rr = 0; rr < 4; ++rr) {
                int m = m0 + wm + i * 16 + fq * 4 + rr;
                int n = n0 + wn + j * 16 + fl;
                float v = acc[i][j][rr];
                if (EPI == 0) {
                    Cf[((size_t)z * NN + m) * H2 + n] = v;
                } else if (EPI == 1) {
                    if (n < Nvalid) Cf[(size_t)m * ldc + n] = v + bias[n];
                } else {
                    if (n < Nvalid)
                        Cb[(size_t)m * KP1 + NODELEN + n] = (n == 0) ? (__bf16)0.f : (__bf16)v;
                }
            }
        }
    }
}

// distinct names for profiler visibility
__global__ __launch_bounds__(256, 4) void k_gemm_h2(
        const __bf16* __restrict__ A2b, const __bf16* __restrict__ xTb,
        __bf16* __restrict__ embb) {
    gemm_body<2, false>(A2b, NN, xTb, NN, NODELEN, FPAD, NN, NN / BK, NN / BK,
                        (float*)nullptr, 0, (const float*)nullptr, embb);
}

__global__ __launch_bounds__(256, 4) void k_gemm_e2(
        const __bf16* __restrict__ embb, const float* __restrict__ We2,
        float* __restrict__ partials) {
    gemm_body<0, true>(embb, KP1, We2, IN_DIM, H2, H2, IN_DIM, KITERS1, KCHUNK1,
                       partials, 0, (const float*)nullptr, (__bf16*)nullptr);
}

__global__ __launch_bounds__(256, 4) void k_gemm_d3(
        const __bf16* __restrict__ hd_b, const float* __restrict__ Wd3,
        const float* __restrict__ b_d3, float* __restrict__ dec) {
    gemm_body<1, true>(hd_b, H2, Wd3, H2, IN_DIM, IN_DIM, H2, H2 / BK, H2 / BK,
                       dec, IN_DIM, b_d3, (__bf16*)nullptr);
}

// h = relu(sum_z partials + b_e2), float4-vectorized
__global__ void k_reduce(const float* __restrict__ partials,
                         const float* __restrict__ bias, float* __restrict__ h) {
    const int T4 = NN * H2 / 4;
    int i4 = blockIdx.x * 256 + threadIdx.x;
    if (i4 >= T4) return;
    const float4* p = (const float4*)partials;
    float4 s = make_float4(0.f, 0.f, 0.f, 0.f);
#pragma unroll
    for (int zz = 0; zz < SPLITS; ++zz) {
        float4 v = p[(size_t)zz * T4 + i4];
        s.x += v.x; s.y += v.y; s.z += v.z; s.w += v.w;
    }
    const float4 b = *(const float4*)&bias[(i4 * 4) % H2];
    s.x += b.x; s.y += b.y; s.z += b.z; s.w += b.w;
    s.x = s.x > 0.f ? s.x : 0.f;
    s.y = s.y > 0.f ? s.y : 0.f;
    s.z = s.z > 0.f ? s.z : 0.f;
    s.w = s.w > 0.f ? s.w : 0.f;
    *(float4*)&h[(size_t)i4 * 4] = s;
}

// encoded[m][e] = h[m] . W_e3[e] + b_e3[e]
__global__ void k_enc(const float* __restrict__ h, const float* __restrict__ W,
                      const float* __restrict__ b, float* __restrict__ out) {
    int m = blockIdx.x, e = threadIdx.x;
    const float4* hr = (const float4*)(h + (size_t)m * H2);
    const float4* wr = (const float4*)(W + (size_t)e * H2);
    float s = 0.f;
#pragma unroll 4
    for (int i = 0; i < H2 / 4; ++i) {
        float4 a = hr[i];
        float4 w = wr[i];
        s += a.x * w.x + a.y * w.y + a.z * w.z + a.w * w.w;
    }
    out[(size_t)m * EMB + e] = s + b[e];
}

// hd_b[m][j] = bf16(relu(enc[m] . W_d1[j] + b_d1[j]))
__global__ void k_dec1(const float* __restrict__ enc, const float* __restrict__ W,
                       const float* __restrict__ b, __bf16* __restrict__ hd) {
    int m = blockIdx.x;
    __shared__ float er[EMB];
    if (threadIdx.x < EMB) er[threadIdx.x] = enc[(size_t)m * EMB + threadIdx.x];
    __syncthreads();
    for (int j = threadIdx.x; j < H2; j += 256) {
        const float4* wr = (const float4*)(W + (size_t)j * EMB);
        float s = 0.f;
#pragma unroll
        for (int i = 0; i < EMB / 4; ++i) {
            float4 w = wr[i];
            s += w.x * er[4 * i] + w.y * er[4 * i + 1] + w.z * er[4 * i + 2] +
                 w.w * er[4 * i + 3];
        }
        float v = s + b[j];
        hd[(size_t)m * H2 + j] = (__bf16)(v > 0.f ? v : 0.f);
    }
}

// ---------------- launch ----------------

extern "C" void kernel_launch(void* const* d_in, const int* in_sizes, int n_in,
                              void* d_out, int out_size, void* d_ws, size_t ws_size,
                              hipStream_t stream) {
    const float* x = (const float*)d_in[0];
    const int* esrc = (const int*)d_in[1];
    const int* edst = (const int*)d_in[2];
    const float* W_e2 = (const float*)d_in[3];
    const float* b_e2 = (const float*)d_in[4];
    const float* W_e3 = (const float*)d_in[5];
    const float* b_e3 = (const float*)d_in[6];
    const float* W_d1 = (const float*)d_in[7];
    const float* b_d1 = (const float*)d_in[8];
    const float* W_d3 = (const float*)d_in[9];
    const float* b_d3 = (const float*)d_in[10];
    float* out = (float*)d_out;

    char* w = (char*)d_ws;
    auto alloc = [&](size_t bytes) {
        char* p = w;
        w += (bytes + 255) & ~(size_t)255;
        return p;
    };
    __bf16* embb = (__bf16*)alloc((size_t)NN * KP1 * 2);           // 36.77 MB
    // scratch union: [xTb | A | A2b | cnt | invdeg] overlaid later by partials
    char* uni = (char*)alloc((size_t)SPLITS * NN * H2 * 4);        // 37.75 MB
    __bf16* xTb = (__bf16*)uni;                                    // FPAD*512*2 = 18.48 MB
    float* Adj = (float*)(uni + (size_t)FPAD * NN * 2);            // 1 MB
    __bf16* A2b = (__bf16*)((char*)Adj + (size_t)NN * NN * 4);     // 0.5 MB
    int* cnt = (int*)((char*)A2b + (size_t)NN * NN * 2);           // 2 KB
    float* invdeg = (float*)((char*)cnt + 2048);                   // 2 KB
    float* partials = (float*)uni;                                 // overlays (safe after h2-GEMM)
    float* h = (float*)alloc((size_t)NN * H2 * 4);
    __bf16* hd_b = (__bf16*)alloc((size_t)NN * H2 * 2);

    // --- adjacency prep ---
    k_zero_int<<<2, 256, 0, stream>>>(cnt, NN);
    k_zero_f4<<<256, 256, 0, stream>>>((float4*)Adj, NN * NN / 4);
    k_deg<<<NE / 256, 256, 0, stream>>>(edst, cnt);
    k_invdeg<<<2, 256, 0, stream>>>(cnt, invdeg);
    k_scatter<<<NE / 256, 256, 0, stream>>>(esrc, edst, invdeg, Adj);
    k_a2<<<NN, 256, 0, stream>>>(Adj, A2b);

    // --- fused x transpose (bf16, rows padded to FPAD) + embb x-half ---
    dim3 gxt(FPAD / 64, NN / 64);
    k_xt_emb<<<gxt, 256, 0, stream>>>(x, xTb, embb);
    k_pad<<<(NN * (KP1 - IN_DIM) + 255) / 256, 256, 0, stream>>>(embb);

    // --- h2 = A2 @ x  -> embb h2-half (bf16, col0 zero) ---
    dim3 gh2(NN / BM, FPAD / BN, 1);
    k_gemm_h2<<<gh2, 256, 0, stream>>>(A2b, xTb, embb);

    // --- GEMM1: emb @ W_e2^T, split-K, W_e2 f32 consumed directly ---
    dim3 g1(NN / BM, H2 / BN, SPLITS);
    k_gemm_e2<<<g1, 256, 0, stream>>>(embb, W_e2, partials);

    k_reduce<<<(NN * H2 / 4 + 255) / 256, 256, 0, stream>>>(partials, b_e2, h);

    // --- encoded ---
    k_enc<<<NN, EMB, 0, stream>>>(h, W_e3, b_e3, out);

    // --- decoder hidden (bf16) ---
    k_dec1<<<NN, 256, 0, stream>>>(out, W_d1, b_d1, hd_b);

    // --- GEMM4: decoded = h_d @ W_d3^T + b_d3, W_d3 f32 consumed directly ---
    dim3 g4(NN / BM, RPAD4 / BN, 1);
    k_gemm_d3<<<g4, 256, 0, stream>>>(hd_b, W_d3, b_d3, out + (size_t)NN * EMB);
}

// Round 5
// 540.867 us; speedup vs baseline: 1.1083x; 1.1083x over previous
//
#include <hip/hip_runtime.h>
#include <hip/hip_bf16.h>

#define NODELEN 17949
#define NN 512
#define NE 4096
#define H2 768
#define EMB 128
#define IN_DIM (2 * NODELEN)      // 35898
#define KP1 35904                 // IN_DIM padded to 64 (561 * 64)
#define KITERS1 561
#define SPLITS 24
#define KCHUNK1 24                // ceil(561/24)
#define FPAD 18048                // NODELEN padded to 64/128
#define RPAD4 35968               // IN_DIM padded to 64 (562 * 64)

#define BM 128
#define BN 64
#define BK 64

typedef __bf16 bf16x8 __attribute__((ext_vector_type(8)));
typedef float f32x4 __attribute__((ext_vector_type(4)));

#define GPTR(p) ((const __attribute__((address_space(1))) void*)(p))
#define LPTR(p) ((__attribute__((address_space(3))) void*)(p))

// ---------------- graph prep (dense adjacency) ----------------

__global__ void k_zero_int(int* p, int n) {
    int i = blockIdx.x * 256 + threadIdx.x;
    if (i < n) p[i] = 0;
}

__global__ void k_zero_f4(float4* p, int n4) {
    int i = blockIdx.x * 256 + threadIdx.x;
    if (i < n4) p[i] = make_float4(0.f, 0.f, 0.f, 0.f);
}

__global__ void k_deg(const int* __restrict__ dst, int* __restrict__ cnt) {
    int e = blockIdx.x * 256 + threadIdx.x;
    if (e < NE) atomicAdd(&cnt[dst[e]], 1);
}

__global__ void k_invdeg(const int* __restrict__ cnt, float* __restrict__ invdeg) {
    int i = blockIdx.x * 256 + threadIdx.x;
    if (i < NN) {
        int c = cnt[i];
        invdeg[i] = 1.0f / (float)(c > 1 ? c : 1);
    }
}

// A[dst][src] += 1/deg[dst]  (duplicates accumulate identical values -> order-safe)
__global__ void k_scatter(const int* __restrict__ src, const int* __restrict__ dst,
                          const float* __restrict__ invdeg, float* __restrict__ A) {
    int e = blockIdx.x * 256 + threadIdx.x;
    if (e < NE) {
        int d = dst[e];
        atomicAdd(&A[(size_t)d * NN + src[e]], invdeg[d]);
    }
}

// A2b = bf16(A @ A), exploiting row sparsity (uniform branch on broadcast value)
__global__ void k_a2(const float* __restrict__ A, __bf16* __restrict__ A2b) {
    int i = blockIdx.x;
    int t = threadIdx.x;   // 256
    __shared__ float row[NN];
    row[t] = A[(size_t)i * NN + t];
    row[t + 256] = A[(size_t)i * NN + 256 + t];
    __syncthreads();
    float a0 = 0.f, a1 = 0.f;
    for (int s = 0; s < NN; ++s) {
        float a = row[s];
        if (a != 0.f) {
            a0 += a * A[(size_t)s * NN + t];
            a1 += a * A[(size_t)s * NN + 256 + t];
        }
    }
    A2b[(size_t)i * NN + t] = (__bf16)a0;
    A2b[(size_t)i * NN + 256 + t] = (__bf16)a1;
}

// Fused: xT[f][s] = bf16(x[s][f]) for f < FPAD (zero rows beyond NODELEN)
// AND embb x-half (col0 zero). Reads x exactly once.
__global__ void k_xt_emb(const float* __restrict__ x, __bf16* __restrict__ xT,
                         __bf16* __restrict__ embb) {
    __shared__ float t[64][65];
    int f0 = blockIdx.x * 64, s0 = blockIdx.y * 64;
    int tx = threadIdx.x & 63, ty = threadIdx.x >> 6;   // ty 0..3
#pragma unroll
    for (int r = 0; r < 16; ++r) {
        int f = f0 + tx;
        int s = s0 + ty * 16 + r;
        float v = (f < NODELEN) ? x[(size_t)s * NODELEN + f] : 0.f;
        t[ty * 16 + r][tx] = v;
        if (f < NODELEN)
            embb[(size_t)s * KP1 + f] = (__bf16)((f == 0) ? 0.f : v);
    }
    __syncthreads();
#pragma unroll
    for (int r = 0; r < 16; ++r) {
        int f = f0 + ty * 16 + r;
        if (f < FPAD) xT[(size_t)f * NN + s0 + tx] = (__bf16)t[tx][ty * 16 + r];
    }
}

// zero pad cols [IN_DIM, KP1) of embb
__global__ void k_pad(__bf16* __restrict__ embb) {
    int i = blockIdx.x * 256 + threadIdx.x;
    const int PAD = KP1 - IN_DIM;   // 6
    if (i < NN * PAD) {
        int n = i / PAD, c = i % PAD;
        embb[(size_t)n * KP1 + IN_DIM + c] = (__bf16)0.f;
    }
}

// generic f32[R][C] -> bf16[Rpad][Cpad] converter, zero-fills pad region
__global__ void k_cvt(const float* __restrict__ src, __bf16* __restrict__ dst,
                      int R, int C, int Rpad, int Cpad) {
    int C8 = Cpad / 8;
    int idx = blockIdx.x * 256 + threadIdx.x;
    if (idx >= Rpad * C8) return;
    int r = idx / C8, c8 = (idx % C8) * 8;
    __align__(16) __bf16 o[8];
    if (r < R && c8 + 8 <= C) {
        const float2* p = (const float2*)(src + (size_t)r * C + c8);
#pragma unroll
        for (int j = 0; j < 4; ++j) {
            float2 f = p[j];
            o[2 * j] = (__bf16)f.x;
            o[2 * j + 1] = (__bf16)f.y;
        }
    } else {
#pragma unroll
        for (int j = 0; j < 8; ++j) {
            int c = c8 + j;
            o[j] = (r < R && c < C) ? (__bf16)src[(size_t)r * C + c] : (__bf16)0.f;
        }
    }
    *(uint4*)&dst[(size_t)r * Cpad + c8] = *(uint4*)o;
}

// ---------------- MFMA GEMM: C[m][n] = sum_k A[m][k] * B[n][k], all bf16 ----------------
// m97 structure at BM=128 x BN=64: single-buffer LINEAR LDS (24 KB -> 6 blocks/CU,
// the TLP that actually hides the staging drain), global_load_lds dwordx4 both
// operands (wave-uniform LDS base + lane*16), 2 barriers/K-step, XCD-swizzled
// (logical x fastest -> the 4 m-blocks sharing a B panel land on one XCD's L2).
// B buffers row-padded to BN multiples; Nvalid guards the epilogue only.
// Waves 2m x 2n: per-wave 64x32 output, acc[4][2].
// EPI: 0 = split-K partials, 1 = f32 out + bias, 2 = bf16 out into embb h2-half.

template <int EPI>
__device__ __forceinline__ void gemm_body(
        const __bf16* __restrict__ A, int lda,
        const __bf16* __restrict__ B, int ldb,
        int Nvalid, int kIters, int kChunk,
        float* __restrict__ Cf, int ldc, const float* __restrict__ bias,
        __bf16* __restrict__ Cb) {
    __shared__ __align__(16) __bf16 As[BM * BK];   // 16 KB
    __shared__ __align__(16) __bf16 Bs[BN * BK];   // 8 KB

    const int tid = threadIdx.x;

    // ---- XCD-aware bijective swizzle (dispatch fid -> XCD = fid % 8) ----
    const int gx = gridDim.x, gy = gridDim.y;
    const int nwg = gx * gy * (int)gridDim.z;
    const int fid = blockIdx.x + gx * (blockIdx.y + gy * blockIdx.z);
    const int q = nwg >> 3, r = nwg & 7;
    const int xcd = fid & 7, idx = fid >> 3;
    const int lid = (xcd < r) ? xcd * (q + 1) + idx
                              : r * (q + 1) + (xcd - r) * q + idx;
    const int m0 = (lid % gx) * BM;
    const int rem = lid / gx;
    const int n0 = (rem % gy) * BN;
    const int z = rem / gy;

    int it0 = z * kChunk;
    int it1 = it0 + kChunk;
    if (it1 > kIters) it1 = kIters;

    const int wave = tid >> 6;
    const int lane = tid & 63;
    const int wm = (wave & 1) * 64;      // 2 m-waves
    const int wn = (wave >> 1) * 32;     // 2 n-waves
    const int fl = lane & 15;
    const int fq = lane >> 4;

    // staging geometry: round rr, thread t -> row rr*32 + t/8, cols (t&7)*8.
    // LDS byte addr = rr*4096 + t*16 = wave-uniform base + lane*16 (GLL pattern).
    const __bf16* Abase = A + (size_t)(m0 + (tid >> 3)) * lda + (tid & 7) * 8;
    const __bf16* Bbase = B + (size_t)(n0 + (tid >> 3)) * ldb + (tid & 7) * 8;
    char* AsW = (char*)As + wave * 1024;
    char* BsW = (char*)Bs + wave * 1024;

    f32x4 acc[4][2] = {};

    for (int it = it0; it < it1; ++it) {
        const __bf16* Ag = Abase + it * BK;
        const __bf16* Bg = Bbase + it * BK;
#pragma unroll
        for (int rr = 0; rr < 4; ++rr)
            __builtin_amdgcn_global_load_lds(
                GPTR(Ag + (size_t)rr * 32 * lda), LPTR(AsW + rr * 4096), 16, 0, 0);
#pragma unroll
        for (int rr = 0; rr < 2; ++rr)
            __builtin_amdgcn_global_load_lds(
                GPTR(Bg + (size_t)rr * 32 * ldb), LPTR(BsW + rr * 4096), 16, 0, 0);
        __syncthreads();   // compiler drains vmcnt before s_barrier

#pragma unroll
        for (int ks = 0; ks < 2; ++ks) {
            const int kk = ks * 32 + fq * 8;
            bf16x8 af[4], bfr[2];
#pragma unroll
            for (int i = 0; i < 4; ++i)
                af[i] = *(const bf16x8*)&As[(wm + i * 16 + fl) * BK + kk];
#pragma unroll
            for (int j = 0; j < 2; ++j)
                bfr[j] = *(const bf16x8*)&Bs[(wn + j * 16 + fl) * BK + kk];
#pragma unroll
            for (int i = 0; i < 4; ++i)
#pragma unroll
                for (int j = 0; j < 2; ++j)
                    acc[i][j] = __builtin_amdgcn_mfma_f32_16x16x32_bf16(
                        af[i], bfr[j], acc[i][j], 0, 0, 0);
        }
        __syncthreads();
    }

    // epilogue
#pragma unroll
    for (int i = 0; i < 4; ++i) {
#pragma unroll
        for (int j = 0; j < 2; ++j) {
#pragma unroll
            for (int rr = 0; rr < 4; ++rr) {
                int m = m0 + wm + i * 16 + fq * 4 + rr;
                int n = n0 + wn + j * 16 + fl;
                float v = acc[i][j][rr];
                if (EPI == 0) {
                    Cf[((size_t)z * NN + m) * H2 + n] = v;
                } else if (EPI == 1) {
                    if (n < Nvalid) Cf[(size_t)m * ldc + n] = v + bias[n];
                } else {
                    if (n < Nvalid)
                        Cb[(size_t)m * KP1 + NODELEN + n] = (n == 0) ? (__bf16)0.f : (__bf16)v;
                }
            }
        }
    }
}

// distinct names for profiler visibility
__global__ __launch_bounds__(256, 4) void k_gemm_h2(
        const __bf16* __restrict__ A2b, const __bf16* __restrict__ xTb,
        __bf16* __restrict__ embb) {
    gemm_body<2>(A2b, NN, xTb, NN, NODELEN, NN / BK, NN / BK,
                 (float*)nullptr, 0, (const float*)nullptr, embb);
}

__global__ __launch_bounds__(256, 4) void k_gemm_e2(
        const __bf16* __restrict__ embb, const __bf16* __restrict__ We2b,
        float* __restrict__ partials) {
    gemm_body<0>(embb, KP1, We2b, KP1, H2, KITERS1, KCHUNK1,
                 partials, 0, (const float*)nullptr, (__bf16*)nullptr);
}

__global__ __launch_bounds__(256, 4) void k_gemm_d3(
        const __bf16* __restrict__ hd_b, const __bf16* __restrict__ Wd3b,
        const float* __restrict__ b_d3, float* __restrict__ dec) {
    gemm_body<1>(hd_b, H2, Wd3b, H2, IN_DIM, H2 / BK, H2 / BK,
                 dec, IN_DIM, b_d3, (__bf16*)nullptr);
}

// h = relu(sum_z partials + b_e2), float4-vectorized
__global__ void k_reduce(const float* __restrict__ partials,
                         const float* __restrict__ bias, float* __restrict__ h) {
    const int T4 = NN * H2 / 4;
    int i4 = blockIdx.x * 256 + threadIdx.x;
    if (i4 >= T4) return;
    const float4* p = (const float4*)partials;
    float4 s = make_float4(0.f, 0.f, 0.f, 0.f);
#pragma unroll
    for (int zz = 0; zz < SPLITS; ++zz) {
        float4 v = p[(size_t)zz * T4 + i4];
        s.x += v.x; s.y += v.y; s.z += v.z; s.w += v.w;
    }
    const float4 b = *(const float4*)&bias[(i4 * 4) % H2];
    s.x += b.x; s.y += b.y; s.z += b.z; s.w += b.w;
    s.x = s.x > 0.f ? s.x : 0.f;
    s.y = s.y > 0.f ? s.y : 0.f;
    s.z = s.z > 0.f ? s.z : 0.f;
    s.w = s.w > 0.f ? s.w : 0.f;
    *(float4*)&h[(size_t)i4 * 4] = s;
}

// encoded[m][e] = h[m] . W_e3[e] + b_e3[e]
__global__ void k_enc(const float* __restrict__ h, const float* __restrict__ W,
                      const float* __restrict__ b, float* __restrict__ out) {
    int m = blockIdx.x, e = threadIdx.x;
    const float4* hr = (const float4*)(h + (size_t)m * H2);
    const float4* wr = (const float4*)(W + (size_t)e * H2);
    float s = 0.f;
#pragma unroll 4
    for (int i = 0; i < H2 / 4; ++i) {
        float4 a = hr[i];
        float4 w = wr[i];
        s += a.x * w.x + a.y * w.y + a.z * w.z + a.w * w.w;
    }
    out[(size_t)m * EMB + e] = s + b[e];
}

// hd_b[m][j] = bf16(relu(enc[m] . W_d1[j] + b_d1[j]))
__global__ void k_dec1(const float* __restrict__ enc, const float* __restrict__ W,
                       const float* __restrict__ b, __bf16* __restrict__ hd) {
    int m = blockIdx.x;
    __shared__ float er[EMB];
    if (threadIdx.x < EMB) er[threadIdx.x] = enc[(size_t)m * EMB + threadIdx.x];
    __syncthreads();
    for (int j = threadIdx.x; j < H2; j += 256) {
        const float4* wr = (const float4*)(W + (size_t)j * EMB);
        float s = 0.f;
#pragma unroll
        for (int i = 0; i < EMB / 4; ++i) {
            float4 w = wr[i];
            s += w.x * er[4 * i] + w.y * er[4 * i + 1] + w.z * er[4 * i + 2] +
                 w.w * er[4 * i + 3];
        }
        float v = s + b[j];
        hd[(size_t)m * H2 + j] = (__bf16)(v > 0.f ? v : 0.f);
    }
}

// ---------------- launch ----------------

extern "C" void kernel_launch(void* const* d_in, const int* in_sizes, int n_in,
                              void* d_out, int out_size, void* d_ws, size_t ws_size,
                              hipStream_t stream) {
    const float* x = (const float*)d_in[0];
    const int* esrc = (const int*)d_in[1];
    const int* edst = (const int*)d_in[2];
    const float* W_e2 = (const float*)d_in[3];
    const float* b_e2 = (const float*)d_in[4];
    const float* W_e3 = (const float*)d_in[5];
    const float* b_e3 = (const float*)d_in[6];
    const float* W_d1 = (const float*)d_in[7];
    const float* b_d1 = (const float*)d_in[8];
    const float* W_d3 = (const float*)d_in[9];
    const float* b_d3 = (const float*)d_in[10];
    float* out = (float*)d_out;

    char* w = (char*)d_ws;
    auto alloc = [&](size_t bytes) {
        char* p = w;
        w += (bytes + 255) & ~(size_t)255;
        return p;
    };
    __bf16* embb = (__bf16*)alloc((size_t)NN * KP1 * 2);           // 36.77 MB
    // scratch union: [xTb | A | A2b | cnt | invdeg] overlaid later by partials
    char* uni = (char*)alloc((size_t)SPLITS * NN * H2 * 4);        // 37.75 MB
    __bf16* xTb = (__bf16*)uni;                                    // FPAD*512*2 = 18.48 MB
    float* Adj = (float*)(uni + (size_t)FPAD * NN * 2);            // 1 MB
    __bf16* A2b = (__bf16*)((char*)Adj + (size_t)NN * NN * 4);     // 0.5 MB
    int* cnt = (int*)((char*)A2b + (size_t)NN * NN * 2);           // 2 KB
    float* invdeg = (float*)((char*)cnt + 2048);                   // 2 KB
    float* partials = (float*)uni;                                 // overlays (safe after h2-GEMM)
    // Wbig: holds We2b for GEMM1, then Wd3b overlays it after GEMM1 completes
    char* Wbig = alloc((size_t)RPAD4 * H2 * 2);                    // 55.25 MB (>= 768*KP1*2)
    __bf16* We2b = (__bf16*)Wbig;
    __bf16* Wd3b = (__bf16*)Wbig;
    float* h = (float*)alloc((size_t)NN * H2 * 4);
    __bf16* hd_b = (__bf16*)alloc((size_t)NN * H2 * 2);

    // --- adjacency prep ---
    k_zero_int<<<2, 256, 0, stream>>>(cnt, NN);
    k_zero_f4<<<256, 256, 0, stream>>>((float4*)Adj, NN * NN / 4);
    k_deg<<<NE / 256, 256, 0, stream>>>(edst, cnt);
    k_invdeg<<<2, 256, 0, stream>>>(cnt, invdeg);
    k_scatter<<<NE / 256, 256, 0, stream>>>(esrc, edst, invdeg, Adj);
    k_a2<<<NN, 256, 0, stream>>>(Adj, A2b);

    // --- fused x transpose (bf16, rows padded to FPAD) + embb x-half ---
    dim3 gxt(FPAD / 64, NN / 64);
    k_xt_emb<<<gxt, 256, 0, stream>>>(x, xTb, embb);
    k_pad<<<(NN * (KP1 - IN_DIM) + 255) / 256, 256, 0, stream>>>(embb);

    // --- h2 = A2 @ x  -> embb h2-half (bf16, col0 zero) ---
    dim3 gh2(NN / BM, FPAD / BN, 1);
    k_gemm_h2<<<gh2, 256, 0, stream>>>(A2b, xTb, embb);

    // --- W_e2 -> bf16 [768][KP1] ---
    k_cvt<<<(H2 * (KP1 / 8) + 255) / 256, 256, 0, stream>>>(
        W_e2, We2b, H2, IN_DIM, H2, KP1);

    // --- GEMM1: emb @ W_e2^T, split-K (overlays scratch with partials) ---
    dim3 g1(NN / BM, H2 / BN, SPLITS);
    k_gemm_e2<<<g1, 256, 0, stream>>>(embb, We2b, partials);

    // --- W_d3 -> bf16 [RPAD4][768] (reuses We2b space; after GEMM1 in stream order) ---
    k_cvt<<<(RPAD4 * (H2 / 8) + 255) / 256, 256, 0, stream>>>(
        W_d3, Wd3b, IN_DIM, H2, RPAD4, H2);

    k_reduce<<<(NN * H2 / 4 + 255) / 256, 256, 0, stream>>>(partials, b_e2, h);

    // --- encoded ---
    k_enc<<<NN, EMB, 0, stream>>>(h, W_e3, b_e3, out);

    // --- decoder hidden (bf16) ---
    k_dec1<<<NN, 256, 0, stream>>>(out, W_d1, b_d1, hd_b);

    // --- GEMM4: decoded = h_d @ W_d3^T + b_d3 ---
    dim3 g4(NN / BM, RPAD4 / BN, 1);
    k_gemm_d3<<<g4, 256, 0, stream>>>(hd_b, Wd3b, b_d3, out + (size_t)NN * EMB);
}